// Round 6
// baseline (185.121 us; speedup 1.0000x reference)
//
#include <hip/hip_runtime.h>

typedef __bf16 bf16;
typedef __bf16 bf16x4 __attribute__((ext_vector_type(4)));
typedef __bf16 bf16x8 __attribute__((ext_vector_type(8)));
typedef float  f32x4  __attribute__((ext_vector_type(4)));

#define MFMA16(a, b, c) __builtin_amdgcn_mfma_f32_16x16x32_bf16((a), (b), (c), 0, 0, 0)

// One block per batch element. 256 threads = 4 waves; wave w owns k-rows [32w,32w+32).
// R6 restructure:
//  * GEMM flipped: acc = W2·muT (A=W2 frags, B=mu frags; same bytes, swapped roles).
//    D layout: col=lane&15=k_node -> each wave reads ONLY ITS OWN muS rows => no
//    mu-publish barrier. Epilogue stores are b64 (4 consecutive q per lane).
//  * s2 identity: s2[q] = rowsum_k(W2·muT)[q] -- replaces psum/partMu/w2row matvec.
//    Cross-wave combine of rowsum partials is the ONLY barrier per iteration
//    (ping-pong partRS buffers).
//  * W2 as hi+lo double-bf16 (2 extra MFMAs/tile, pipe is ~5% busy) keeps s2 and
//    per-k W2 error ~2^-17 (s2 was exact fp32 in R5; margin preserved).
// launch_bounds(256,2): NEVER cap VGPR below live set (R2/R4 spill disasters).
__global__ __launch_bounds__(256, 2)
void qnet_kernel(const float* __restrict__ Xg, const float* __restrict__ Wg,
                 const float* __restrict__ W1g, const float* __restrict__ W2g,
                 const float* __restrict__ W3g, const float* __restrict__ W4g,
                 const float* __restrict__ W5g, const float* __restrict__ W6g,
                 const float* __restrict__ W7g, float* __restrict__ Outg)
{
    __shared__ __align__(16) bf16 muS[128 * 72];        // 18432 B, row stride 72
    __shared__ __align__(16) float partRS[2][4][64];    // 2048 B, s2 rowsum partials (ping-pong)
    __shared__ float xs[128], wws[128], W5s[128];       // 1536 B
    __shared__ float partAB[256];                       // 1024 B (u partials, then pooled partials)
    __shared__ __align__(16) float v3pS[64], v3mS[64];  // 512 B
    __shared__ float sumMuS[64], uS[64];                // 512 B

    const int t    = threadIdx.x;
    const int b    = blockIdx.x;
    const int lane = t & 63;
    const int w    = t >> 6;
    const int l15  = lane & 15;
    const int quad = lane >> 4;

    // ---------------- stage per-batch vectors ----------------
    if (t < 128) { xs[t] = Xg[b * 128 + t]; W5s[t] = W5g[t]; }
    else         wws[t - 128] = Wg[b * 128 + t - 128];
    __syncthreads();

    // ---------------- prologue: closed-form tmsg terms (exact fp32) ----------------
    float Ap, Bn;
    {
        float w0 = wws[lane], w1 = wws[64 + lane];
        Ap = fmaxf(w0, 0.f) + fmaxf(w1, 0.f);
        Bn = fmaxf(-w0, 0.f) + fmaxf(-w1, 0.f);
#pragma unroll
        for (int m = 1; m < 64; m <<= 1) { Ap += __shfl_xor(Ap, m); Bn += __shfl_xor(Bn, m); }
    }

    float r4p[16], r4m[16];
#pragma unroll
    for (int c = 0; c < 4; ++c) {
        f32x4 v = *(const f32x4*)&W4g[quad * 16 + c * 4];
#pragma unroll
        for (int e = 0; e < 4; ++e) { r4p[c*4+e] = fmaxf(v[e], 0.f); r4m[c*4+e] = fmaxf(-v[e], 0.f); }
    }

    // v3p[q]=relu(W4)@W3[q,:], v3m[q]=relu(-W4)@W3[q,:]  (q = qt*16+l15) -> LDS
#pragma unroll
    for (int qt = 0; qt < 4; ++qt) {
        const int q = qt * 16 + l15;
        float sp = 0.f, sm = 0.f;
#pragma unroll
        for (int c = 0; c < 4; ++c) {
            f32x4 wv = *(const f32x4*)&W3g[q * 64 + quad * 16 + c * 4];
#pragma unroll
            for (int e = 0; e < 4; ++e) { sp += r4p[c*4+e] * wv[e]; sm += r4m[c*4+e] * wv[e]; }
        }
        sp += __shfl_xor(sp, 16); sp += __shfl_xor(sp, 32);
        sm += __shfl_xor(sm, 16); sm += __shfl_xor(sm, 32);
        if (quad == 0) { v3pS[q] = sp; v3mS[q] = sm; }
    }

    // u = W5b @ W7 partials (q-slice per wave) -> partAB
    {
        float su = 0.f;
#pragma unroll
        for (int i = 0; i < 16; ++i)
            su += W5s[64 + w * 16 + i] * W7g[(w * 16 + i) * 64 + lane];
        partAB[w * 64 + lane] = su;
    }

    // W2 A-fragments hi+lo (double-bf16) from global (one-time, L2-hot)
    bf16x8 w2h[4][2], w2l[4][2];
#pragma unroll
    for (int qt = 0; qt < 4; ++qt)
#pragma unroll
        for (int s = 0; s < 2; ++s) {
            const float* src = &W2g[(qt * 16 + l15) * 64 + s * 32 + quad * 8];
            f32x4 f0 = *(const f32x4*)src;
            f32x4 f1 = *(const f32x4*)(src + 4);
            bf16x8 h, l;
#pragma unroll
            for (int e = 0; e < 4; ++e) {
                bf16 h0 = (bf16)f0[e], h1 = (bf16)f1[e];
                h[e] = h0; h[4 + e] = h1;
                l[e]     = (bf16)(f0[e] - (float)h0);
                l[4 + e] = (bf16)(f1[e] - (float)h1);
            }
            w2h[qt][s] = h; w2l[qt][s] = l;
        }

    // per-lane k scalars (k = w*32 + kt*16 + l15)
    float xk[2], apk[2], bnk[2];
#pragma unroll
    for (int kt = 0; kt < 2; ++kt) {
        const int k = w * 32 + kt * 16 + l15;
        xk[kt] = xs[k];
        float wk = wws[k];
        apk[kt] = Ap - fmaxf(wk, 0.f);
        bnk[kt] = Bn - fmaxf(-wk, 0.f);
    }
    __syncthreads();   // v3pS/v3mS published

    // baseR[kt][qt] (f32x4 over r): base = x_k*W1[q] + (Ap-a_k)*v3p[q] + (Bn-b_k)*v3m[q]
    // (q = qt*16 + quad*4 + r)  -- exact fp32
    f32x4 baseR[2][4];
    {
#pragma unroll
        for (int qt = 0; qt < 4; ++qt) {
            f32x4 w1v = *(const f32x4*)&W1g[qt * 16 + quad * 4];
            f32x4 vp  = *(const f32x4*)&v3pS[qt * 16 + quad * 4];
            f32x4 vm  = *(const f32x4*)&v3mS[qt * 16 + quad * 4];
#pragma unroll
            for (int kt = 0; kt < 2; ++kt) {
#pragma unroll
                for (int e = 0; e < 4; ++e)
                    baseR[kt][qt][e] = xk[kt] * w1v[e] + apk[kt] * vp[e] + bnk[kt] * vm[e];
            }
        }
    }

    // mu1 = relu(base) -> muS rows (own rows, b64 stores, new layout: row k, 4 consecutive q)
#pragma unroll
    for (int kt = 0; kt < 2; ++kt) {
        const int krow = w * 32 + kt * 16 + l15;
#pragma unroll
        for (int qt = 0; qt < 4; ++qt) {
            bf16x4 h;
#pragma unroll
            for (int e = 0; e < 4; ++e) h[e] = (bf16)fmaxf(baseR[kt][qt][e], 0.f);
            *(bf16x4*)&muS[krow * 72 + qt * 16 + quad * 4] = h;
        }
    }

    // ---------------- 3 iterations, ONE barrier each ----------------
    const f32x4 zero4 = {0.f, 0.f, 0.f, 0.f};
    for (int it = 0; it < 3; ++it) {
        // B-frags from OWN muS rows (wave-private, no barrier needed)
        bf16x8 mb[2][2];
#pragma unroll
        for (int kt = 0; kt < 2; ++kt) {
            const int krow = w * 32 + kt * 16 + l15;
            mb[kt][0] = *(bf16x8*)&muS[krow * 72 + quad * 8];
            mb[kt][1] = *(bf16x8*)&muS[krow * 72 + 32 + quad * 8];
        }
        // acc[kt][qt] = (W2hi + W2lo) · muT   (D: row=q=qt*16+quad*4+r, col=k=kt*16+l15)
        f32x4 acc[2][4];
#pragma unroll
        for (int kt = 0; kt < 2; ++kt)
#pragma unroll
            for (int qt = 0; qt < 4; ++qt) {
                f32x4 a = MFMA16(w2h[qt][0], mb[kt][0], zero4);
                a = MFMA16(w2h[qt][1], mb[kt][1], a);
                a = MFMA16(w2l[qt][0], mb[kt][0], a);
                a = MFMA16(w2l[qt][1], mb[kt][1], a);
                acc[kt][qt] = a;
            }

        // s2 partial = rowsum_k(acc) over this wave's 32 k: in-thread kt-add + l15 butterfly
        f32x4 rs[4];
#pragma unroll
        for (int qt = 0; qt < 4; ++qt) rs[qt] = acc[0][qt] + acc[1][qt];
#pragma unroll
        for (int m = 1; m <= 8; m <<= 1)
#pragma unroll
            for (int qt = 0; qt < 4; ++qt)
#pragma unroll
                for (int e = 0; e < 4; ++e)
                    rs[qt][e] += __shfl_xor(rs[qt][e], m);
        if (l15 == 0) {
#pragma unroll
            for (int qt = 0; qt < 4; ++qt)
                *(f32x4*)&partRS[it & 1][w][qt * 16 + quad * 4] = rs[qt];
        }
        __syncthreads();   // the ONE barrier: partRS published (ping-pong -> no WAR race)

        // s2 combine + epilogue + own-row stores
#pragma unroll
        for (int qt = 0; qt < 4; ++qt) {
            const float* p0 = &partRS[it & 1][0][qt * 16 + quad * 4];
            f32x4 s2v = (*(const f32x4*)p0        + *(const f32x4*)(p0 + 64)) +
                        (*(const f32x4*)(p0+128)  + *(const f32x4*)(p0 + 192));
#pragma unroll
            for (int kt = 0; kt < 2; ++kt) {
                const int krow = w * 32 + kt * 16 + l15;
                bf16x4 h;
#pragma unroll
                for (int e = 0; e < 4; ++e) {
                    float v = fmaxf(baseR[kt][qt][e] + s2v[e] - acc[kt][qt][e], 0.f);
                    h[e] = (bf16)v;
                }
                *(bf16x4*)&muS[krow * 72 + qt * 16 + quad * 4] = h;
            }
        }
    }

    // ---------------- readout ----------------
    __syncthreads();   // R1: all muS rows visible block-wide
    if (t < 64) uS[t] = partAB[t] + partAB[64 + t] + partAB[128 + t] + partAB[192 + t];
    // colsum partial: thread (w, p=lane) sums its 32 rows (stride-1 across lanes: conflict-free)
    {
        float cs = 0.f;
#pragma unroll 8
        for (int j = 0; j < 32; ++j) cs += (float)muS[(w * 32 + j) * 72 + lane];
        ((float*)partRS)[w * 64 + lane] = cs;   // partRS free after loop
    }
    __syncthreads();   // R2: uS + colsum partials ready
    if (t < 64) {
        const float* csb = (const float*)partRS;
        sumMuS[t] = csb[t] + csb[64 + t] + csb[128 + t] + csb[192 + t];
    }
    __syncthreads();   // R3: sumMuS ready; partAB free (uS consumed pre-R2)
    {
        float pp = 0.f;
#pragma unroll
        for (int c = 0; c < 4; ++c) {
            f32x4 wv = *(const f32x4*)&W6g[lane * 64 + w * 16 + c * 4];
#pragma unroll
            for (int e = 0; e < 4; ++e) pp += sumMuS[w * 16 + c * 4 + e] * wv[e];
        }
        partAB[w * 64 + lane] = pp;
    }
    __syncthreads();   // R4: pooled partials ready

    float qa = 0.f;
#pragma unroll
    for (int i = 0; i < 16; ++i) {
        const int q = quad * 16 + i;
        float pl = fmaxf(partAB[q] + partAB[64 + q] + partAB[128 + q] + partAB[192 + q], 0.f);
        qa += pl * W5s[q];
    }
    qa += __shfl_xor(qa, 16); qa += __shfl_xor(qa, 32);

    if (t < 128) {
        float accq = qa;
#pragma unroll
        for (int j = 0; j < 8; ++j) {
            bf16x8 m8 = *(bf16x8*)&muS[t * 72 + j * 8];
#pragma unroll
            for (int e = 0; e < 8; ++e) accq += (float)m8[e] * uS[j * 8 + e];
        }
        Outg[b * 128 + t] = accq;
    }
}

extern "C" void kernel_launch(void* const* d_in, const int* in_sizes, int n_in,
                              void* d_out, int out_size, void* d_ws, size_t ws_size,
                              hipStream_t stream) {
    (void)n_in; (void)d_ws; (void)ws_size; (void)out_size;
    const int B = in_sizes[0] >> 7;   // 4096
    qnet_kernel<<<B, 256, 0, stream>>>(
        (const float*)d_in[0], (const float*)d_in[1], (const float*)d_in[2],
        (const float*)d_in[3], (const float*)d_in[4], (const float*)d_in[5],
        (const float*)d_in[6], (const float*)d_in[7], (const float*)d_in[8],
        (float*)d_out);
}

// Round 7
// 138.397 us; speedup vs baseline: 1.3376x; 1.3376x over previous
//
#include <hip/hip_runtime.h>

typedef __bf16 bf16;
typedef __bf16 bf16x4 __attribute__((ext_vector_type(4)));
typedef __bf16 bf16x8 __attribute__((ext_vector_type(8)));
typedef float  f32x4  __attribute__((ext_vector_type(4)));

#define MFMA16(a, b, c) __builtin_amdgcn_mfma_f32_16x16x32_bf16((a), (b), (c), 0, 0, 0)

// R7: ONE WAVE PER BATCH ELEMENT, ZERO BARRIERS.
// Grid 4096 x 64. The flipped GEMM (acc = W2·muT, D col=lane&15=k) makes the s2
// rowsum reducible entirely within the wave (in-lane kt adds + 4-step l15
// butterfly) -> no cross-wave combine -> no __syncthreads anywhere. All LDS use
// is wave-private (compiler lgkmcnt ordering suffices).
// Two-pass K-loop per iteration: pass1 = hi+lo bf16 W2 MFMAs -> s2 (~fp32 W2
// accuracy); pass2 = hi-only MFMA recompute + epilogue with base RECOMPUTED from
// 72 const regs (xk/apk/bnk per kt; W1/v3p/v3m per (qt,e)) instead of 128 stored
// fp32 -> VGPR ~200, under the 256 cliff. R2/R4 lesson: spills (FETCH_SIZE
// explosion) are catastrophic -- launch_bounds(64,2) caps at 256, est. live ~200.
// LDS 18.9KB -> 8 blocks/CU = 8 free-running waves/CU.
__global__ __launch_bounds__(64, 2)
void qnet_kernel(const float* __restrict__ Xg, const float* __restrict__ Wg,
                 const float* __restrict__ W1g, const float* __restrict__ W2g,
                 const float* __restrict__ W3g, const float* __restrict__ W4g,
                 const float* __restrict__ W5g, const float* __restrict__ W6g,
                 const float* __restrict__ W7g, float* __restrict__ Outg)
{
    __shared__ __align__(16) bf16 muS[128 * 72];   // 18432 B, row k stride 72 halfwords
    __shared__ __align__(16) float uS[64];         // 256 B
    __shared__ __align__(16) float smS[64];        // 256 B

    const int lane = threadIdx.x;       // 0..63, one wave
    const int b    = blockIdx.x;
    const int l15  = lane & 15;
    const int quad = lane >> 4;

    // ---------------- per-batch vectors (registers only) ----------------
    float xv0 = Xg[b * 128 + lane], xv1 = Xg[b * 128 + 64 + lane];
    float wv0 = Wg[b * 128 + lane], wv1 = Wg[b * 128 + 64 + lane];

    float Ap = fmaxf(wv0, 0.f) + fmaxf(wv1, 0.f);
    float Bn = fmaxf(-wv0, 0.f) + fmaxf(-wv1, 0.f);
#pragma unroll
    for (int m = 1; m < 64; m <<= 1) { Ap += __shfl_xor(Ap, m); Bn += __shfl_xor(Bn, m); }

    // per-kt scalars via shfl (k = kt*16 + l15)
    float xk[8], apk[8], bnk[8];
#pragma unroll
    for (int kt = 0; kt < 8; ++kt) {
        const int src = (kt & 3) * 16 + l15;
        float xs_ = (kt < 4) ? __shfl(xv0, src) : __shfl(xv1, src);
        float ws_ = (kt < 4) ? __shfl(wv0, src) : __shfl(wv1, src);
        xk[kt]  = xs_;
        apk[kt] = Ap - fmaxf(ws_, 0.f);
        bnk[kt] = Bn - fmaxf(-ws_, 0.f);
    }

    // v3p[q]=relu(W4)@W3[q,:], v3m[q]=relu(-W4)@W3[q,:]  (lane computes q=lane, exact fp32)
    float sp = 0.f, sm = 0.f;
#pragma unroll
    for (int c = 0; c < 16; ++c) {
        f32x4 w4 = *(const f32x4*)&W4g[c * 4];
        f32x4 w3 = *(const f32x4*)&W3g[lane * 64 + c * 4];
#pragma unroll
        for (int e = 0; e < 4; ++e) {
            sp += fmaxf(w4[e], 0.f) * w3[e];
            sm += fmaxf(-w4[e], 0.f) * w3[e];
        }
    }
    // distribute to (qt,e) epilogue layout: q = qt*16 + quad*4 + e
    float v3pC[16], v3mC[16], w1C[16];
#pragma unroll
    for (int qt = 0; qt < 4; ++qt) {
        f32x4 w1v = *(const f32x4*)&W1g[qt * 16 + quad * 4];
#pragma unroll
        for (int e = 0; e < 4; ++e) {
            const int q = qt * 16 + quad * 4 + e;
            v3pC[qt * 4 + e] = __shfl(sp, q);
            v3mC[qt * 4 + e] = __shfl(sm, q);
            w1C[qt * 4 + e]  = w1v[e];
        }
    }

    // W2 A-fragments hi+lo (double-bf16), flipped-GEMM layout (A row = q = l15)
    bf16x8 w2h[4][2], w2l[4][2];
#pragma unroll
    for (int qt = 0; qt < 4; ++qt)
#pragma unroll
        for (int s = 0; s < 2; ++s) {
            const float* src = &W2g[(qt * 16 + l15) * 64 + s * 32 + quad * 8];
            f32x4 f0 = *(const f32x4*)src;
            f32x4 f1 = *(const f32x4*)(src + 4);
            bf16x8 h, l;
#pragma unroll
            for (int e = 0; e < 4; ++e) {
                bf16 h0 = (bf16)f0[e], h1 = (bf16)f1[e];
                h[e] = h0; h[4 + e] = h1;
                l[e]     = (bf16)(f0[e] - (float)h0);
                l[4 + e] = (bf16)(f1[e] - (float)h1);
            }
            w2h[qt][s] = h; w2l[qt][s] = l;
        }

    // u[p=lane] = sum_q' W5b[q'] * W7[q'][p]  -> uS (wave-private LDS)
    {
        float u = 0.f;
#pragma unroll
        for (int c = 0; c < 16; ++c) {
            f32x4 w5v = *(const f32x4*)&W5g[64 + c * 4];
#pragma unroll
            for (int e = 0; e < 4; ++e)
                u += w5v[e] * W7g[(c * 4 + e) * 64 + lane];
        }
        uS[lane] = u;
    }

    // mu1 = relu(base), base = xk*W1[q] + apk*v3p[q] + bnk*v3m[q]  (exact fp32)
#pragma unroll
    for (int kt = 0; kt < 8; ++kt) {
        const int row = (kt * 16 + l15) * 72;
#pragma unroll
        for (int qt = 0; qt < 4; ++qt) {
            bf16x4 h;
#pragma unroll
            for (int e = 0; e < 4; ++e) {
                float t = fmaf(xk[kt], w1C[qt * 4 + e],
                          fmaf(apk[kt], v3pC[qt * 4 + e], bnk[kt] * v3mC[qt * 4 + e]));
                h[e] = (bf16)fmaxf(t, 0.f);
            }
            *(bf16x4*)&muS[row + qt * 16 + quad * 4] = h;
        }
    }

    // ---------------- 3 iterations, zero barriers ----------------
    const f32x4 zero4 = {0.f, 0.f, 0.f, 0.f};
    float smv[16];
#pragma unroll
    for (int i = 0; i < 16; ++i) smv[i] = 0.f;

    for (int it = 0; it < 3; ++it) {
        // pass1: s2 = rowsum_k(W2·muT), hi+lo W2 (s2 at ~fp32-W2 accuracy)
        f32x4 rs[4] = {zero4, zero4, zero4, zero4};
#pragma unroll
        for (int kt = 0; kt < 8; ++kt) {
            const int row = (kt * 16 + l15) * 72;
            bf16x8 m0 = *(bf16x8*)&muS[row + quad * 8];
            bf16x8 m1 = *(bf16x8*)&muS[row + 32 + quad * 8];
#pragma unroll
            for (int qt = 0; qt < 4; ++qt) {
                f32x4 a = MFMA16(w2h[qt][0], m0, zero4);
                a = MFMA16(w2h[qt][1], m1, a);
                a = MFMA16(w2l[qt][0], m0, a);
                a = MFMA16(w2l[qt][1], m1, a);
                rs[qt] += a;
            }
        }
#pragma unroll
        for (int m = 1; m <= 8; m <<= 1)
#pragma unroll
            for (int qt = 0; qt < 4; ++qt)
#pragma unroll
                for (int e = 0; e < 4; ++e)
                    rs[qt][e] += __shfl_xor(rs[qt][e], m);
        // rs[qt][e] now holds s2[q] for q = qt*16+quad*4+e, on every lane

        // pass2: recompute acc (hi W2) + fused epilogue, stores wave-private
#pragma unroll
        for (int kt = 0; kt < 8; ++kt) {
            const int row = (kt * 16 + l15) * 72;
            bf16x8 m0 = *(bf16x8*)&muS[row + quad * 8];
            bf16x8 m1 = *(bf16x8*)&muS[row + 32 + quad * 8];
#pragma unroll
            for (int qt = 0; qt < 4; ++qt) {
                f32x4 a = MFMA16(w2h[qt][0], m0, zero4);
                a = MFMA16(w2h[qt][1], m1, a);
                bf16x4 h;
#pragma unroll
                for (int e = 0; e < 4; ++e) {
                    float t = fmaf(xk[kt], w1C[qt * 4 + e], rs[qt][e]);
                    t = fmaf(apk[kt], v3pC[qt * 4 + e], t);
                    t = fmaf(bnk[kt], v3mC[qt * 4 + e], t);
                    float v = fmaxf(t - a[e], 0.f);
                    h[e] = (bf16)v;
                    if (it == 2) smv[qt * 4 + e] += v;   // colsum of final mu
                }
                *(bf16x4*)&muS[row + qt * 16 + quad * 4] = h;
            }
        }
    }

    // ---------------- readout (all wave-internal) ----------------
    // sumMu: finish colsum butterfly over l15, publish via smS
#pragma unroll
    for (int m = 1; m <= 8; m <<= 1)
#pragma unroll
        for (int i = 0; i < 16; ++i) smv[i] += __shfl_xor(smv[i], m);
    if (l15 == 0) {
#pragma unroll
        for (int qt = 0; qt < 4; ++qt) {
            f32x4 v = {smv[qt * 4 + 0], smv[qt * 4 + 1], smv[qt * 4 + 2], smv[qt * 4 + 3]};
            *(f32x4*)&smS[qt * 16 + quad * 4] = v;
        }
    }

    // pooled[q=lane] = relu(sumMu @ W6[lane,:]); qa = sum_q pooled*W5a
    float pl = 0.f;
#pragma unroll
    for (int c = 0; c < 16; ++c) {
        f32x4 sv  = *(const f32x4*)&smS[c * 4];
        f32x4 w6v = *(const f32x4*)&W6g[lane * 64 + c * 4];
#pragma unroll
        for (int e = 0; e < 4; ++e) pl += sv[e] * w6v[e];
    }
    float qa = fmaxf(pl, 0.f) * W5g[lane];
#pragma unroll
    for (int m = 1; m < 64; m <<= 1) qa += __shfl_xor(qa, m);

    // out[k] = qa + mu[k,:]·u   (k = lane, lane+64)
#pragma unroll
    for (int h2 = 0; h2 < 2; ++h2) {
        const int k = lane + 64 * h2;
        float accq = qa;
#pragma unroll
        for (int j = 0; j < 8; ++j) {
            bf16x8 m8 = *(bf16x8*)&muS[k * 72 + j * 8];
            f32x4 u0 = *(const f32x4*)&uS[j * 8];
            f32x4 u1 = *(const f32x4*)&uS[j * 8 + 4];
#pragma unroll
            for (int e = 0; e < 4; ++e) accq += (float)m8[e] * u0[e];
#pragma unroll
            for (int e = 0; e < 4; ++e) accq += (float)m8[4 + e] * u1[e];
        }
        Outg[b * 128 + k] = accq;
    }
}

extern "C" void kernel_launch(void* const* d_in, const int* in_sizes, int n_in,
                              void* d_out, int out_size, void* d_ws, size_t ws_size,
                              hipStream_t stream) {
    (void)n_in; (void)d_ws; (void)ws_size; (void)out_size;
    const int B = in_sizes[0] >> 7;   // 4096
    qnet_kernel<<<B, 64, 0, stream>>>(
        (const float*)d_in[0], (const float*)d_in[1], (const float*)d_in[2],
        (const float*)d_in[3], (const float*)d_in[4], (const float*)d_in[5],
        (const float*)d_in[6], (const float*)d_in[7], (const float*)d_in[8],
        (float*)d_out);
}